// Round 1
// baseline (376.354 us; speedup 1.0000x reference)
//
#include <hip/hip_runtime.h>
#include <math.h>

// Problem dims (fixed by the reference setup): B=4, C=64, H=512, W=512, fp32.
#define HH 512
#define WW 512
#define IMG (HH * WW)
#define NDIL 3

__global__ __launch_bounds__(256) void lap3_kernel(const float* __restrict__ u,
                                                   const float* __restrict__ D,
                                                   float* __restrict__ out) {
    // Each thread computes 4 consecutive pixels (one aligned float4).
    const int p = blockIdx.x * 256 + threadIdx.x;   // float4 index over the whole tensor
    const int w4 = (p & (WW / 4 - 1)) << 2;         // 128 float4s per row
    const int h  = (p >> 7) & (HH - 1);
    const int bc = p >> 16;                         // 65536 float4s per channel image
    const int c  = bc & 63;                         // C = 64

    const float* __restrict__ img = u + (size_t)bc * IMG;
    const float* __restrict__ row = img + h * WW;

    // Per-(dilation, channel) softplus scales (numerically stable form).
    float s[NDIL];
#pragma unroll
    for (int i = 0; i < NDIL; ++i) {
        float x = D[i * 64 + c];
        float ax = fabsf(x);
        s[i] = fmaxf(x, 0.0f) + log1pf(expf(-ax));
    }
    const float csum = s[0] + s[1] + s[2];

    const float4 ctr = *reinterpret_cast<const float4*>(row + w4);
    const float ctr_a[4] = {ctr.x, ctr.y, ctr.z, ctr.w};

    float acc[4] = {0.f, 0.f, 0.f, 0.f};

    const int ds[NDIL] = {1, 4, 16};
#pragma unroll
    for (int i = 0; i < NDIL; ++i) {
        const int d = ds[i];
        const int hm = max(h - d, 0);
        const int hp = min(h + d, HH - 1);
        const float4 up = *reinterpret_cast<const float4*>(img + hm * WW + w4);
        const float4 dn = *reinterpret_cast<const float4*>(img + hp * WW + w4);
        const float up_a[4] = {up.x, up.y, up.z, up.w};
        const float dn_a[4] = {dn.x, dn.y, dn.z, dn.w};
#pragma unroll
        for (int j = 0; j < 4; ++j) {
            const int w = w4 + j;
            const int wm = max(w - d, 0);
            const int wp = min(w + d, WW - 1);
            const float l = row[wm];
            const float r = row[wp];
            acc[j] = fmaf(s[i], up_a[j] + dn_a[j] + l + r, acc[j]);
        }
    }

    float4 o;
    o.x = fmaf(-4.0f * csum, ctr_a[0], acc[0]);
    o.y = fmaf(-4.0f * csum, ctr_a[1], acc[1]);
    o.z = fmaf(-4.0f * csum, ctr_a[2], acc[2]);
    o.w = fmaf(-4.0f * csum, ctr_a[3], acc[3]);

    *reinterpret_cast<float4*>(out + (size_t)bc * IMG + h * WW + w4) = o;
}

extern "C" void kernel_launch(void* const* d_in, const int* in_sizes, int n_in,
                              void* d_out, int out_size, void* d_ws, size_t ws_size,
                              hipStream_t stream) {
    const float* u = (const float*)d_in[0];
    const float* D = (const float*)d_in[1];
    float* out = (float*)d_out;

    // total float4s = 4*64*512*512 / 4 = 16777216 -> 65536 blocks of 256
    const int n4 = out_size / 4;
    const int blocks = n4 / 256;
    lap3_kernel<<<blocks, 256, 0, stream>>>(u, D, out);
}

// Round 3
// 189.506 us; speedup vs baseline: 1.9860x; 1.9860x over previous
//
#include <hip/hip_runtime.h>
#include <math.h>

// Problem dims (fixed by the reference setup): B=4, C=64, H=512, W=512, fp32.
#define HH 512
#define WW 512
#define W4 (WW / 4)     // 128 float4 per row
#define IMG (HH * WW)

typedef float f32x4 __attribute__((ext_vector_type(4)));

__device__ __forceinline__ float4 bcast(float v) { return make_float4(v, v, v, v); }

__global__ __launch_bounds__(256) void lap3_kernel(const float* __restrict__ u,
                                                   const float* __restrict__ D,
                                                   float* __restrict__ out) {
    // XCD-contiguous swizzle: 65536 blocks, 8 XCDs -> each XCD owns a
    // contiguous 8192-block run (contiguous rows) so the +/-16 row halo
    // stays in its private 4MB L2.
    const int bid = blockIdx.x;
    const int swz = (bid & 7) * 8192 + (bid >> 3);
    const int p = swz * 256 + threadIdx.x;          // float4 index over tensor

    const int q  = p & (W4 - 1);                    // float4 col 0..127
    const int w4 = q << 2;                          // pixel col of component 0
    const int h  = (p >> 7) & (HH - 1);
    const int bc = p >> 16;                         // (b*64 + c)
    const int c  = bc & 63;

    const float* __restrict__ img = u + (size_t)bc * IMG;
    const float* __restrict__ row = img + h * WW;
    const float4* __restrict__ row4 = reinterpret_cast<const float4*>(row);
    const float4* __restrict__ img4 = reinterpret_cast<const float4*>(img);

    // softplus scales (wave-uniform: bc constant within a wave)
    float s0, s1, s2;
    {
        float x0 = D[c], x1 = D[64 + c], x2 = D[128 + c];
        s0 = fmaxf(x0, 0.0f) + log1pf(expf(-fabsf(x0)));
        s1 = fmaxf(x1, 0.0f) + log1pf(expf(-fabsf(x1)));
        s2 = fmaxf(x2, 0.0f) + log1pf(expf(-fabsf(x2)));
    }
    const float m4c = -4.0f * (s0 + s1 + s2);

    const float4 ctr = row4[q];

    // vertical neighbors (aligned float4, clamped rows)
    const int hm1 = max(h - 1, 0),  hp1 = min(h + 1, HH - 1);
    const int hm4 = max(h - 4, 0),  hp4 = min(h + 4, HH - 1);
    const int hm16 = max(h - 16, 0), hp16 = min(h + 16, HH - 1);
    const float4 u1 = img4[hm1 * W4 + q],  d1 = img4[hp1 * W4 + q];
    const float4 u4 = img4[hm4 * W4 + q],  d4 = img4[hp4 * W4 + q];
    const float4 u16 = img4[hm16 * W4 + q], d16 = img4[hp16 * W4 + q];

    // horizontal d=4: shift by one float4 (aligned), boundary = broadcast
    float4 l4 = row4[max(q - 1, 0)];
    if (q == 0) l4 = bcast(l4.x);
    float4 r4 = row4[min(q + 1, W4 - 1)];
    if (q == W4 - 1) r4 = bcast(r4.w);

    // horizontal d=16: shift by four float4s (aligned)
    float4 l16 = row4[max(q - 4, 0)];
    if (q < 4) l16 = bcast(l16.x);
    float4 r16 = row4[min(q + 4, W4 - 1)];
    if (q > W4 - 5) r16 = bcast(r16.w);

    // horizontal d=1: two scalars + center register
    const float la = row[max(w4 - 1, 0)];
    const float rb = row[min(w4 + 4, WW - 1)];
    const float l1[4] = {la, ctr.x, ctr.y, ctr.z};
    const float r1[4] = {ctr.y, ctr.z, ctr.w, rb};

    const float u1a[4] = {u1.x, u1.y, u1.z, u1.w};
    const float d1a[4] = {d1.x, d1.y, d1.z, d1.w};
    const float u4a[4] = {u4.x, u4.y, u4.z, u4.w};
    const float d4a[4] = {d4.x, d4.y, d4.z, d4.w};
    const float u16a[4] = {u16.x, u16.y, u16.z, u16.w};
    const float d16a[4] = {d16.x, d16.y, d16.z, d16.w};
    const float l4a[4] = {l4.x, l4.y, l4.z, l4.w};
    const float r4a[4] = {r4.x, r4.y, r4.z, r4.w};
    const float l16a[4] = {l16.x, l16.y, l16.z, l16.w};
    const float r16a[4] = {r16.x, r16.y, r16.z, r16.w};
    const float ca[4] = {ctr.x, ctr.y, ctr.z, ctr.w};

    float o[4];
#pragma unroll
    for (int j = 0; j < 4; ++j) {
        float acc = m4c * ca[j];
        acc = fmaf(s0, (u1a[j] + d1a[j]) + (l1[j] + r1[j]), acc);
        acc = fmaf(s1, (u4a[j] + d4a[j]) + (l4a[j] + r4a[j]), acc);
        acc = fmaf(s2, (u16a[j] + d16a[j]) + (l16a[j] + r16a[j]), acc);
        o[j] = acc;
    }

    f32x4 ov = {o[0], o[1], o[2], o[3]};
    f32x4* dst = reinterpret_cast<f32x4*>(out + (size_t)bc * IMG + h * WW + w4);
    __builtin_nontemporal_store(ov, dst);
}

extern "C" void kernel_launch(void* const* d_in, const int* in_sizes, int n_in,
                              void* d_out, int out_size, void* d_ws, size_t ws_size,
                              hipStream_t stream) {
    const float* u = (const float*)d_in[0];
    const float* D = (const float*)d_in[1];
    float* out = (float*)d_out;

    const int n4 = out_size / 4;        // 16777216 float4s
    const int blocks = n4 / 256;        // 65536 blocks
    lap3_kernel<<<blocks, 256, 0, stream>>>(u, D, out);
}

// Round 4
// 106.049 us; speedup vs baseline: 3.5489x; 1.7870x over previous
//
#include <hip/hip_runtime.h>
#include <math.h>

// Problem dims (fixed by the reference setup): B=4, C=64, H=512, W=512, fp32.
#define HH 512
#define WW 512
#define W4 128          // float4s per row
#define IMG (HH * WW)

typedef float f32x4 __attribute__((ext_vector_type(4)));

__device__ __forceinline__ f32x4 bc4(float v) { f32x4 r = {v, v, v, v}; return r; }

// Tiny pre-kernel: softplus(D) for all 3*64 (dilation, channel) pairs.
__global__ void scales_kernel(const float* __restrict__ D, float* __restrict__ s) {
    const int i = threadIdx.x;
    if (i < 192) {
        const float x = D[i];
        s[i] = fmaxf(x, 0.0f) + log1pf(expf(-fabsf(x)));
    }
}

template<bool CLAMP>
__device__ __forceinline__ void compute_tile(const f32x4* __restrict__ img4,
                                             f32x4* __restrict__ out4,
                                             int h0, int q,
                                             float s0, float s1, float s2, float m4c)
{
    auto ld = [&](int r) -> f32x4 {
        const int rr = CLAMP ? (r < 0 ? 0 : (r > HH - 1 ? HH - 1 : r)) : r;
        return img4[rr * W4 + q];
    };

    // Vertical row set for 4 output rows h0..h0+3 (all aligned float4 at col q).
    f32x4 C[6];                       // rows h0-1 .. h0+4 (d=1 + reuse for d=4)
#pragma unroll
    for (int k = 0; k < 6; ++k) C[k] = ld(h0 - 1 + k);
    f32x4 U4[3], D4[3];               // d=4: h0-4..h0-2 and h0+5..h0+7
#pragma unroll
    for (int k = 0; k < 3; ++k) U4[k] = ld(h0 - 4 + k);
#pragma unroll
    for (int k = 0; k < 3; ++k) D4[k] = ld(h0 + 5 + k);
    f32x4 U16[4], D16[4];             // d=16: h0-16..h0-13 and h0+16..h0+19
#pragma unroll
    for (int k = 0; k < 4; ++k) U16[k] = ld(h0 - 16 + k);
#pragma unroll
    for (int k = 0; k < 4; ++k) D16[k] = ld(h0 + 16 + k);

    // Horizontal quad indices / boundary predicates: computed once per thread.
    const int qm1 = max(q - 1, 0), qp1 = min(q + 1, W4 - 1);
    const int qm4 = max(q - 4, 0), qp4 = min(q + 4, W4 - 1);
    const bool pl4 = (q == 0), pr4 = (q == W4 - 1);
    const bool pl16 = (q < 4), pr16 = (q > W4 - 5);

#pragma unroll
    for (int r = 0; r < 4; ++r) {
        const int rr = h0 + r;                      // always in [0,511]
        const f32x4* __restrict__ rowq = img4 + rr * W4;

        f32x4 l4 = rowq[qm1];  if (pl4)  l4 = bc4(l4.x);
        f32x4 r4 = rowq[qp1];  if (pr4)  r4 = bc4(r4.w);
        f32x4 l16 = rowq[qm4]; if (pl16) l16 = bc4(l16.x);
        f32x4 r16 = rowq[qp4]; if (pr16) r16 = bc4(r16.w);

        const f32x4 cc  = C[r + 1];
        const f32x4 up1 = C[r], dn1 = C[r + 2];
        const f32x4 up4 = (r < 3) ? U4[r] : C[0];
        const f32x4 dn4 = (r == 0) ? C[5] : D4[r - 1];
        const f32x4 u16v = U16[r], d16v = D16[r];

        // d=1 horizontal: neighbors come from center regs + l4.w / r4.x
        // (post-fixup these are exactly the edge-replicated values).
        f32x4 l1 = { l4.w, cc.x, cc.y, cc.z };
        f32x4 r1 = { cc.y, cc.z, cc.w, r4.x };

        const f32x4 d1s  = (up1 + dn1) + (l1 + r1);
        const f32x4 d4s  = (up4 + dn4) + (l4 + r4);
        const f32x4 d16s = (u16v + d16v) + (l16 + r16);

        f32x4 o;
#pragma unroll
        for (int j = 0; j < 4; ++j) {
            float acc = m4c * cc[j];
            acc = fmaf(s0, d1s[j], acc);
            acc = fmaf(s1, d4s[j], acc);
            acc = fmaf(s2, d16s[j], acc);
            o[j] = acc;
        }
        __builtin_nontemporal_store(o, out4 + rr * W4 + q);
    }
}

__global__ __launch_bounds__(256) void lap3_kernel(const float* __restrict__ u,
                                                   const float* __restrict__ S,
                                                   float* __restrict__ out) {
    // XCD-contiguous swizzle over 16384 blocks: each XCD owns a contiguous
    // 2048-block run (contiguous rows) so row halos stay in its private L2.
    const int bid = blockIdx.x;
    const int swz = (bid & 7) * 2048 + (bid >> 3);
    const int p = swz * 256 + threadIdx.x;

    const int q  = p & (W4 - 1);          // float4 col 0..127
    const int hg = (p >> 7) & 127;        // row-group (4 rows each)
    const int h0 = hg << 2;
    const int bc = p >> 14;               // (b*64 + c)
    const int c  = bc & 63;

    const float s0 = S[c], s1 = S[64 + c], s2 = S[128 + c];
    const float m4c = -4.0f * (s0 + s1 + s2);

    const f32x4* img4 = reinterpret_cast<const f32x4*>(u) + (size_t)bc * (IMG / 4);
    f32x4* out4 = reinterpret_cast<f32x4*>(out) + (size_t)bc * (IMG / 4);

    if (h0 >= 16 && h0 <= HH - 20)        // wave-uniform (hg uniform per wave)
        compute_tile<false>(img4, out4, h0, q, s0, s1, s2, m4c);
    else
        compute_tile<true>(img4, out4, h0, q, s0, s1, s2, m4c);
}

extern "C" void kernel_launch(void* const* d_in, const int* in_sizes, int n_in,
                              void* d_out, int out_size, void* d_ws, size_t ws_size,
                              hipStream_t stream) {
    const float* u = (const float*)d_in[0];
    const float* D = (const float*)d_in[1];
    float* out = (float*)d_out;
    float* S = (float*)d_ws;              // 192 floats

    scales_kernel<<<1, 192, 0, stream>>>(D, S);

    const int n4 = out_size / 4;          // 16777216 float4s
    const int blocks = n4 / (256 * 4);    // 4 rows per thread -> 16384 blocks
    lap3_kernel<<<blocks, 256, 0, stream>>>(u, S, out);
}